// Round 8
// baseline (231.741 us; speedup 1.0000x reference)
//
#include <hip/hip_runtime.h>
#include <hip/hip_bf16.h>

#define B_    8
#define N_    9225
#define M_    4096
#define K_    32
#define HID_  64
#define DOUT_ 16

typedef __attribute__((ext_vector_type(8))) short short8;
typedef __attribute__((ext_vector_type(4))) float floatx4;
typedef __attribute__((ext_vector_type(2))) float f32x2;

static __device__ __forceinline__ short f2bf(float f) {
    __hip_bfloat16 h = __float2bfloat16(f);
    return __builtin_bit_cast(short, h);
}
static __device__ __forceinline__ float bf2f(short s) {
    unsigned u = ((unsigned)(unsigned short)s) << 16;
    return __builtin_bit_cast(float, u);
}
static __device__ __forceinline__ f32x2 splat2(float v) { return (f32x2){v, v}; }

// Sum over each 16-lane DPP row via row_shr tree; lane (row*16+15) holds the sum.
static __device__ __forceinline__ float row16_sum(float v) {
    int t;
    t = __builtin_amdgcn_update_dpp(0, __builtin_bit_cast(int, v), 0x111, 0xF, 0xF, true);
    v += __builtin_bit_cast(float, t);
    t = __builtin_amdgcn_update_dpp(0, __builtin_bit_cast(int, v), 0x112, 0xF, 0xF, true);
    v += __builtin_bit_cast(float, t);
    t = __builtin_amdgcn_update_dpp(0, __builtin_bit_cast(int, v), 0x114, 0xF, 0xF, true);
    v += __builtin_bit_cast(float, t);
    t = __builtin_amdgcn_update_dpp(0, __builtin_bit_cast(int, v), 0x118, 0xF, 0xF, true);
    v += __builtin_bit_cast(float, t);
    return v;
}

// Packed-Pade gelu (R13-validated, absmax 0.0625).
static __device__ __forceinline__ f32x2 gelu2(f32x2 x) {
    const f32x2 xsq = x * x;
    const f32x2 t   = __builtin_elementwise_fma(xsq, splat2(0.035677408f), splat2(0.79788456f));
    const f32x2 z   = x * t;
    const f32x2 u   = z * z;
    const f32x2 a   = u + splat2(105.0f);
    const f32x2 nin = __builtin_elementwise_fma(u, a, splat2(945.0f));
    const f32x2 num = z * nin;
    const f32x2 bq  = __builtin_elementwise_fma(u, splat2(15.0f), splat2(420.0f));
    const f32x2 den = __builtin_elementwise_fma(u, bq, splat2(945.0f));
    const f32x2 r   = { __builtin_amdgcn_rcpf(den[0]), __builtin_amdgcn_rcpf(den[1]) };
    f32x2 th = num * r;
    th = __builtin_elementwise_min(__builtin_elementwise_max(th, splat2(-1.0f)), splat2(1.0f));
    const f32x2 hx = x * splat2(0.5f);
    return __builtin_elementwise_fma(hx, th, hx);
}

// R19: DECOMPOSITION ROUND. Seven structural variants (R12-R18: VALU +-30%,
// occupancy 30->50%, VGPR 164->40, MFMA count, barriers, addresses 144->80,
// prologues, 24-deep burst) all left it_kernel pinned at 39-44us; VALUBusy
// always ~= occupancy x duty ~= 50%. Two surviving models: H-latency (waves
// serially eat scattered-gather latency; compiler defeats pipelining) vs
// H-issue (real per-phase instruction cost ~2x static estimate). This round
// measures instead of guessing: V0 = exact R18 (output, graded, passes);
// V1 = compute-only (synthetic fv/sw/yv2 from bn, REP=4 to clear the 42us
// fill floor in top-5); V2 = gather-only (loads kept live via sum, REP=2,
// rep-salted indices to defeat CSE). V1/V2 write to workspace. One-round
// dur_us regression accepted to buy the decisive counters.
template<int V, int REP>
__global__ __launch_bounds__(256, 2) void it_kernel(
    const float* __restrict__ y,
    const float* __restrict__ x,
    const float* __restrict__ f_y,
    const float* __restrict__ weights,
    const float* __restrict__ W1,   // [4][64] row-major
    const float* __restrict__ b1,   // [64]
    const float* __restrict__ W2,   // [64][16] row-major
    const float* __restrict__ b2,   // [16]
    const int*   __restrict__ nbr,  // [B][M][K] int32
    float*       __restrict__ outp) // V0: [B][M][16]; V1/V2: ws region
{
    const int tid  = threadIdx.x;
    const int lane = tid & 63;
    const int q    = lane >> 4;    // quad 0..3
    const int nlo  = lane & 15;
    const bool q0  = (q == 0);

    const int blk   = blockIdx.x;
    const int batch = blk & 7;          // XCD pin (round-robin heuristic)
    const int pblk  = blk >> 3;         // 0..255 within batch
    const int wid   = tid >> 6;         // wave 0..3
    const int row0  = __builtin_amdgcn_readfirstlane(batch * M_ + pblk * 16 + wid * 4);
    const int bbase = batch * N_;

    // ---- neighbor indices for all 8 phases (coalesced; kept in ALL variants) ----
    int raw[8];
    #pragma unroll
    for (int ph = 0; ph < 8; ++ph) {
        const int it = ph >> 1, h = ph & 1;
        raw[ph] = nbr[(size_t)(row0 + it) * K_ + h * 16 + nlo];
    }

    // ---- W1^T A-fragments, hi/lo k-packed (R14-validated) ----
    short8 w1h[4];
    #pragma unroll
    for (int t = 0; t < 4; ++t) {
        #pragma unroll
        for (int jj = 0; jj < 4; ++jj) {
            const float wv = W1[jj * HID_ + t * 16 + nlo];
            const short b  = q0 ? f2bf(wv) : (short)0;
            w1h[t][jj]     = b;
            w1h[t][jj + 4] = b;
        }
    }

    // ---- W2 A-fragment with layer-1-layout re-index (R13-validated) ----
    short8 w2f[2];
    #pragma unroll
    for (int ch = 0; ch < 2; ++ch)
        #pragma unroll
        for (int jj = 0; jj < 8; ++jj) {
            const int H = (ch * 2 + (jj >> 2)) * 16 + q * 4 + (jj & 3);
            w2f[ch][jj] = f2bf(W2[H * DOUT_ + nlo]);
        }

    // ---- biases in VGPRs (zero LDS, zero barriers) ----
    floatx4 b1r[4];
    #pragma unroll
    for (int t = 0; t < 4; ++t)
        b1r[t] = *(const floatx4*)(b1 + t * 16 + q * 4);
    const floatx4 b2r = *(const floatx4*)(b2 + q * 4);

    // ---- per-row x hi/lo bf16 (4 rows) ----
    short xh[8], xl[8];
    #pragma unroll
    for (int it = 0; it < 4; ++it) {
        const float2 xv = *(const float2*)(x + (size_t)(row0 + it) * 2);
        const short h0 = f2bf(xv.x); const short l0 = f2bf(xv.x - bf2f(h0));
        const short h1 = f2bf(xv.y); const short l1 = f2bf(xv.y - bf2f(h1));
        xh[it * 2] = h0; xh[it * 2 + 1] = h1;
        xl[it * 2] = l0; xl[it * 2 + 1] = l1;
    }

    float2 yv2[8]; float sw[8]; floatx4 fv[8];
    #pragma unroll
    for (int i = 0; i < 8; ++i) yv2[i] = (float2){0.0f, 0.0f};

    float gsum = 0.0f;   // V2 keep-live accumulator

    #pragma unroll
    for (int rep = 0; rep < REP; ++rep) {
        // ---- BURST: all 8 phases' gathers (V0/V2) or synthetics (V1) ----
        #pragma unroll
        for (int P = 0; P < 8; ++P) {
            const int rv  = raw[P];
            const int vld = rv >= 0;
            int idx = vld ? rv : 0;
            idx += rep * 1031;                 // salt (folds to 0 for rep==0)
            if (idx >= N_) idx -= N_;
            if (idx >= N_) idx -= N_;          // REP<=4: rep*1031<4124<2*N_
            const int bn = bbase + idx;
            if constexpr (V == 1) {
                const float base = (float)bn * 1.0e-7f * (float)(rep + 1);
                fv[P] = (floatx4){base, base * 1.1f, base * 1.2f, base * 1.3f};
                sw[P] = vld ? base : 0.0f;
                if (q0) yv2[P] = (float2){base * 0.5f, base * 0.7f};
            } else {
                fv[P] = *(const floatx4*)(f_y + (size_t)bn * 16 + q * 4);
                const float wv_ = weights[bn];
                sw[P] = vld ? wv_ : 0.0f;
                if (q0) yv2[P] = *(const float2*)(y + (size_t)bn * 2);
            }
        }
        __builtin_amdgcn_sched_barrier(0);

        if constexpr (V == 2) {
            // gather-only: consume loads data-dependently (no DCE)
            #pragma unroll
            for (int P = 0; P < 8; ++P)
                gsum += fv[P][0] + fv[P][1] + fv[P][2] + fv[P][3]
                      + sw[P] + yv2[P].x + yv2[P].y;
            continue;
        }

        float partial[4] = {0.f, 0.f, 0.f, 0.f};
        #pragma unroll
        for (int ph = 0; ph < 8; ++ph) {
            const int it = ph >> 1;

            const float y0 = yv2[ph].x, y1 = yv2[ph].y;
            const short yh0 = f2bf(y0); const short yl0 = f2bf(y0 - bf2f(yh0));
            const short yh1 = f2bf(y1); const short yl1 = f2bf(y1 - bf2f(yh1));
            const short8 bfull = { yh0, yh1, xh[it * 2], xh[it * 2 + 1],
                                   yl0, yl1, xl[it * 2], xl[it * 2 + 1] };

            floatx4 a1[4];
            #pragma unroll
            for (int t = 0; t < 4; ++t) {
                a1[t] = b1r[t];
                a1[t] = __builtin_amdgcn_mfma_f32_16x16x32_bf16(w1h[t], bfull, a1[t], 0, 0, 0);
            }

            short hv[16];
            #pragma unroll
            for (int t = 0; t < 4; ++t) {
                const f32x2 g01 = gelu2((f32x2){a1[t][0], a1[t][1]});
                const f32x2 g23 = gelu2((f32x2){a1[t][2], a1[t][3]});
                hv[t * 4 + 0] = f2bf(g01[0]); hv[t * 4 + 1] = f2bf(g01[1]);
                hv[t * 4 + 2] = f2bf(g23[0]); hv[t * 4 + 3] = f2bf(g23[1]);
            }
            const short8 hf0 = {hv[0], hv[1], hv[2],  hv[3],  hv[4],  hv[5],  hv[6],  hv[7]};
            const short8 hf1 = {hv[8], hv[9], hv[10], hv[11], hv[12], hv[13], hv[14], hv[15]};

            floatx4 acc = b2r;
            acc = __builtin_amdgcn_mfma_f32_16x16x32_bf16(w2f[0], hf0, acc, 0, 0, 0);
            acc = __builtin_amdgcn_mfma_f32_16x16x32_bf16(w2f[1], hf1, acc, 0, 0, 0);

            const floatx4 fvp = fv[ph];
            const float   s   = sw[ph];
            #pragma unroll
            for (int r = 0; r < 4; ++r)
                partial[r] = fmaf(acc[r], fvp[r] * s, partial[r]);

            if (ph & 1) {
                #pragma unroll
                for (int r = 0; r < 4; ++r) partial[r] = row16_sum(partial[r]);
                if (nlo == 15) {
                    floatx4 o = {partial[0], partial[1], partial[2], partial[3]};
                    *(floatx4*)(outp + (size_t)(row0 + it) * DOUT_ + q * 4) = o;
                }
                #pragma unroll
                for (int r = 0; r < 4; ++r) partial[r] = 0.f;
            }
        }
    }

    if constexpr (V == 2) {
        outp[(size_t)blk * 256 + tid] = gsum;
    }
}

extern "C" void kernel_launch(void* const* d_in, const int* in_sizes, int n_in,
                              void* d_out, int out_size, void* d_ws, size_t ws_size,
                              hipStream_t stream) {
    const float* y   = (const float*)d_in[0];
    const float* x   = (const float*)d_in[1];
    const float* f_y = (const float*)d_in[2];
    const float* w   = (const float*)d_in[3];
    const float* W1  = (const float*)d_in[4];
    const float* b1  = (const float*)d_in[5];
    const float* W2  = (const float*)d_in[6];
    const float* b2  = (const float*)d_in[7];
    const int*   nbr = (const int*)d_in[8];
    float* out = (float*)d_out;

    dim3 grid(B_ * M_ / 16), block(256);

    // V0: the real (graded) kernel -- exact R18.
    hipLaunchKernelGGL(HIP_KERNEL_NAME(it_kernel<0, 1>), grid, block, 0, stream,
                       y, x, f_y, w, W1, b1, W2, b2, nbr, out);

    // Diagnostics into workspace (guarded). V1 needs 2MB at +0; V2 writes
    // 2MB at +16MB. One-round timing cost, decisive counters.
    if (d_ws != nullptr && ws_size >= (size_t)32 * 1024 * 1024) {
        float* ws1 = (float*)d_ws;
        float* ws2 = (float*)((char*)d_ws + (size_t)16 * 1024 * 1024);
        hipLaunchKernelGGL(HIP_KERNEL_NAME(it_kernel<1, 4>), grid, block, 0, stream,
                           y, x, f_y, w, W1, b1, W2, b2, nbr, ws1);
        hipLaunchKernelGGL(HIP_KERNEL_NAME(it_kernel<2, 2>), grid, block, 0, stream,
                           y, x, f_y, w, W1, b1, W2, b2, nbr, ws2);
    }
}

// Round 9
// 105.100 us; speedup vs baseline: 2.2049x; 2.2049x over previous
//
#include <hip/hip_runtime.h>
#include <hip/hip_bf16.h>

#define B_    8
#define N_    9225
#define M_    4096
#define K_    32
#define HID_  64
#define DOUT_ 16

typedef __attribute__((ext_vector_type(8))) short short8;
typedef __attribute__((ext_vector_type(4))) float floatx4;
typedef __attribute__((ext_vector_type(2))) float f32x2;
typedef __attribute__((ext_vector_type(4))) unsigned uint4v;

static __device__ __forceinline__ short f2bf(float f) {
    __hip_bfloat16 h = __float2bfloat16(f);
    return __builtin_bit_cast(short, h);
}
static __device__ __forceinline__ f32x2 splat2(float v) { return (f32x2){v, v}; }

// gfx950 v_cvt_pk_bf16_f32: two f32 -> one u32 holding {lo=bf16(a), hi=bf16(b)}.
// One instruction replaces ~10 (2x RNE-emulated __float2bfloat16 + packing).
// No builtin on gfx950 (guide T12) -> inline asm. Pure-VALU asm: register
// deps tracked by operands, no waitcnt hazard (rule #18 applies to ds_read).
static __device__ __forceinline__ unsigned cvtpk(float a, float b) {
    unsigned r;
    asm("v_cvt_pk_bf16_f32 %0, %1, %2" : "=v"(r) : "v"(a), "v"(b));
    return r;
}
// f32 views of the two bf16 halves of a packed word (for residual computation)
static __device__ __forceinline__ float pk_lo_f(unsigned u) {
    return __builtin_bit_cast(float, u << 16);
}
static __device__ __forceinline__ float pk_hi_f(unsigned u) {
    return __builtin_bit_cast(float, u & 0xffff0000u);
}

// Sum over each 16-lane DPP row via row_shr tree; lane (row*16+15) holds the sum.
static __device__ __forceinline__ float row16_sum(float v) {
    int t;
    t = __builtin_amdgcn_update_dpp(0, __builtin_bit_cast(int, v), 0x111, 0xF, 0xF, true);
    v += __builtin_bit_cast(float, t);
    t = __builtin_amdgcn_update_dpp(0, __builtin_bit_cast(int, v), 0x112, 0xF, 0xF, true);
    v += __builtin_bit_cast(float, t);
    t = __builtin_amdgcn_update_dpp(0, __builtin_bit_cast(int, v), 0x114, 0xF, 0xF, true);
    v += __builtin_bit_cast(float, t);
    t = __builtin_amdgcn_update_dpp(0, __builtin_bit_cast(int, v), 0x118, 0xF, 0xF, true);
    v += __builtin_bit_cast(float, t);
    return v;
}

// Packed-Pade gelu (R13-validated, absmax 0.0625).
static __device__ __forceinline__ f32x2 gelu2(f32x2 x) {
    const f32x2 xsq = x * x;
    const f32x2 t   = __builtin_elementwise_fma(xsq, splat2(0.035677408f), splat2(0.79788456f));
    const f32x2 z   = x * t;
    const f32x2 u   = z * z;
    const f32x2 a   = u + splat2(105.0f);
    const f32x2 nin = __builtin_elementwise_fma(u, a, splat2(945.0f));
    const f32x2 num = z * nin;
    const f32x2 bq  = __builtin_elementwise_fma(u, splat2(15.0f), splat2(420.0f));
    const f32x2 den = __builtin_elementwise_fma(u, bq, splat2(945.0f));
    const f32x2 r   = { __builtin_amdgcn_rcpf(den[0]), __builtin_amdgcn_rcpf(den[1]) };
    f32x2 th = num * r;
    th = __builtin_elementwise_min(__builtin_elementwise_max(th, splat2(-1.0f)), splat2(1.0f));
    const f32x2 hx = x * splat2(0.5f);
    return __builtin_elementwise_fma(hx, th, hx);
}

// R20: VALU-count attack, guided by R19's decomposition. V1 (compute-only,
// synthetic inputs, REP=4) measured 30.2us/rep at VALUBusy 78% / FETCH 2.7MB
// -> of the ~40us kernel, ~30us is pure compute, gathers ~10us. H-latency
// DEAD (R2-R18's gather engineering targeted 25% of the kernel). Cycle math:
// ~440 VALU instrs/phase, 2.2x static estimate; attribution: 20x RNE-emulated
// __float2bfloat16 (~5 instrs each) + short8 fragment assembly (~16 v_perm).
// Fix: v_cvt_pk_bf16_f32 converts f32 pairs DIRECTLY into fragment words --
// hv path 16 f2bf + packing -> 8 cvt_pk; y hi/lo ~14 -> 6; bfull/hf become
// bit_casts. Est ~270 instrs/phase. Everything else frozen from R18 (burst
// gathers + sched_barrier, zero LDS/barriers, 4 rows/wave, hi/lo k-packed
// layer-1, re-indexed W2 frag, XCD pin). Diagnostics removed.
__global__ __launch_bounds__(256, 2) void it_kernel(
    const float* __restrict__ y,
    const float* __restrict__ x,
    const float* __restrict__ f_y,
    const float* __restrict__ weights,
    const float* __restrict__ W1,   // [4][64] row-major
    const float* __restrict__ b1,   // [64]
    const float* __restrict__ W2,   // [64][16] row-major
    const float* __restrict__ b2,   // [16]
    const int*   __restrict__ nbr,  // [B][M][K] int32
    float*       __restrict__ out)  // [B][M][16]
{
    const int tid  = threadIdx.x;
    const int lane = tid & 63;
    const int q    = lane >> 4;    // quad 0..3
    const int nlo  = lane & 15;
    const bool q0  = (q == 0);

    const int blk   = blockIdx.x;
    const int batch = blk & 7;          // XCD pin (round-robin heuristic)
    const int pblk  = blk >> 3;         // 0..255 within batch
    const int wid   = tid >> 6;         // wave 0..3
    const int row0  = __builtin_amdgcn_readfirstlane(batch * M_ + pblk * 16 + wid * 4);
    const int bbase = batch * N_;

    // ---- neighbor indices for all 8 phases: issue first ----
    int raw[8];
    #pragma unroll
    for (int ph = 0; ph < 8; ++ph) {
        const int it = ph >> 1, h = ph & 1;
        raw[ph] = nbr[(size_t)(row0 + it) * K_ + h * 16 + nlo];
    }

    // ---- W1^T A-fragments, hi/lo k-packed (R14-validated; setup-only cost) ----
    short8 w1h[4];
    #pragma unroll
    for (int t = 0; t < 4; ++t) {
        #pragma unroll
        for (int jj = 0; jj < 4; ++jj) {
            const float wv = W1[jj * HID_ + t * 16 + nlo];
            const short b  = q0 ? f2bf(wv) : (short)0;
            w1h[t][jj]     = b;
            w1h[t][jj + 4] = b;
        }
    }

    // ---- W2 A-fragment with layer-1-layout re-index (R13-validated) ----
    short8 w2f[2];
    #pragma unroll
    for (int ch = 0; ch < 2; ++ch)
        #pragma unroll
        for (int jj = 0; jj < 8; ++jj) {
            const int H = (ch * 2 + (jj >> 2)) * 16 + q * 4 + (jj & 3);
            w2f[ch][jj] = f2bf(W2[H * DOUT_ + nlo]);
        }

    // ---- biases in VGPRs (zero LDS, zero barriers) ----
    floatx4 b1r[4];
    #pragma unroll
    for (int t = 0; t < 4; ++t)
        b1r[t] = *(const floatx4*)(b1 + t * 16 + q * 4);
    const floatx4 b2r = *(const floatx4*)(b2 + q * 4);

    // ---- per-row x hi/lo, packed words (4 rows): word = {bf16 x0, bf16 x1} ----
    unsigned xw_h[4], xw_l[4];
    #pragma unroll
    for (int it = 0; it < 4; ++it) {
        const float2 xv = *(const float2*)(x + (size_t)(row0 + it) * 2);
        const unsigned hw = cvtpk(xv.x, xv.y);
        xw_h[it] = hw;
        xw_l[it] = cvtpk(xv.x - pk_lo_f(hw), xv.y - pk_hi_f(hw));
    }

    // ---- BURST: all 8 phases' gathers issued back-to-back (R18) ----
    float2 yv2[8]; float sw[8]; floatx4 fv[8];
    #pragma unroll
    for (int i = 0; i < 8; ++i) yv2[i] = (float2){0.0f, 0.0f};
    #pragma unroll
    for (int P = 0; P < 8; ++P) {
        const int rv  = raw[P];
        const int vld = rv >= 0;
        const int bn  = bbase + (vld ? rv : 0);
        fv[P] = *(const floatx4*)(f_y + (size_t)bn * 16 + q * 4);
        const float wv_ = weights[bn];
        sw[P] = vld ? wv_ : 0.0f;
        if (q0) yv2[P] = *(const float2*)(y + (size_t)bn * 2);
    }
    __builtin_amdgcn_sched_barrier(0);

    float partial[4] = {0.f, 0.f, 0.f, 0.f};
    #pragma unroll
    for (int ph = 0; ph < 8; ++ph) {
        const int it = ph >> 1;

        // ---- input B-fragment via cvt_pk: word0={yh0,yh1}, word1={xh0,xh1},
        //      word2={yl0,yl1}, word3={xl0,xl1}. 6 VALU + 2 bit_casts. ----
        const float y0 = yv2[ph].x, y1 = yv2[ph].y;
        const unsigned yw_h = cvtpk(y0, y1);
        const unsigned yw_l = cvtpk(y0 - pk_lo_f(yw_h), y1 - pk_hi_f(yw_h));
        const uint4v bw = { yw_h, xw_h[it], yw_l, xw_l[it] };
        const short8 bfull = __builtin_bit_cast(short8, bw);

        // ---- layer 1: one MFMA per 16-hid tile (hi+lo k-packed) ----
        floatx4 a1[4];
        #pragma unroll
        for (int t = 0; t < 4; ++t) {
            a1[t] = b1r[t];
            a1[t] = __builtin_amdgcn_mfma_f32_16x16x32_bf16(w1h[t], bfull, a1[t], 0, 0, 0);
        }

        // ---- gelu (packed) -> cvt_pk directly into B-frag words:
        //      hf0 words = t0:{g0,g1},{g2,g3}, t1:{g0,g1},{g2,g3}; hf1 = t2,t3 ----
        unsigned hw[8];
        #pragma unroll
        for (int t = 0; t < 4; ++t) {
            const f32x2 g01 = gelu2((f32x2){a1[t][0], a1[t][1]});
            const f32x2 g23 = gelu2((f32x2){a1[t][2], a1[t][3]});
            hw[t * 2 + 0] = cvtpk(g01[0], g01[1]);
            hw[t * 2 + 1] = cvtpk(g23[0], g23[1]);
        }
        const uint4v h0w = { hw[0], hw[1], hw[2], hw[3] };
        const uint4v h1w = { hw[4], hw[5], hw[6], hw[7] };
        const short8 hf0 = __builtin_bit_cast(short8, h0w);
        const short8 hf1 = __builtin_bit_cast(short8, h1w);

        // ---- layer 2: kval[c][elem] = W2^T . h + b2 ----
        floatx4 acc = b2r;
        acc = __builtin_amdgcn_mfma_f32_16x16x32_bf16(w2f[0], hf0, acc, 0, 0, 0);
        acc = __builtin_amdgcn_mfma_f32_16x16x32_bf16(w2f[1], hf1, acc, 0, 0, 0);

        const floatx4 fvp = fv[ph];
        const float   s   = sw[ph];          // 0 for invalid neighbors
        #pragma unroll
        for (int r = 0; r < 4; ++r)
            partial[r] = fmaf(acc[r], fvp[r] * s, partial[r]);

        if (ph & 1) {   // finished a row: reduce over 16 elem-lanes, store
            #pragma unroll
            for (int r = 0; r < 4; ++r) partial[r] = row16_sum(partial[r]);
            if (nlo == 15) {
                floatx4 o = {partial[0], partial[1], partial[2], partial[3]};
                *(floatx4*)(out + (size_t)(row0 + it) * DOUT_ + q * 4) = o;
            }
            #pragma unroll
            for (int r = 0; r < 4; ++r) partial[r] = 0.f;
        }
    }
}

extern "C" void kernel_launch(void* const* d_in, const int* in_sizes, int n_in,
                              void* d_out, int out_size, void* d_ws, size_t ws_size,
                              hipStream_t stream) {
    const float* y   = (const float*)d_in[0];
    const float* x   = (const float*)d_in[1];
    const float* f_y = (const float*)d_in[2];
    const float* w   = (const float*)d_in[3];
    const float* W1  = (const float*)d_in[4];
    const float* b1  = (const float*)d_in[5];
    const float* W2  = (const float*)d_in[6];
    const float* b2  = (const float*)d_in[7];
    const int*   nbr = (const int*)d_in[8];
    float* out = (float*)d_out;

    // Single dispatch. 2048 blocks: 256 per batch (16 rows/block),
    // batch = blk & 7 -> XCD pin.
    dim3 grid(B_ * M_ / 16), block(256);
    hipLaunchKernelGGL(it_kernel, grid, block, 0, stream,
                       y, x, f_y, w, W1, b1, W2, b2, nbr, out);
}

// Round 10
// 103.991 us; speedup vs baseline: 2.2285x; 1.0107x over previous
//
#include <hip/hip_runtime.h>
#include <hip/hip_bf16.h>
#include <math.h>

#define B_    8
#define N_    9225
#define M_    4096
#define K_    32
#define HID_  64
#define DOUT_ 16

typedef __attribute__((ext_vector_type(8))) short short8;
typedef __attribute__((ext_vector_type(4))) float floatx4;
typedef __attribute__((ext_vector_type(2))) float f32x2;
typedef __attribute__((ext_vector_type(4))) unsigned uint4v;

static __device__ __forceinline__ short f2bf(float f) {
    __hip_bfloat16 h = __float2bfloat16(f);
    return __builtin_bit_cast(short, h);
}
static __device__ __forceinline__ f32x2 splat2(float v) { return (f32x2){v, v}; }

// cvt_pk for the y hi/lo fragment words (kept from R20 -- neutral there).
static __device__ __forceinline__ unsigned cvtpk(float a, float b) {
    unsigned r;
    asm("v_cvt_pk_bf16_f32 %0, %1, %2" : "=v"(r) : "v"(a), "v"(b));
    return r;
}
static __device__ __forceinline__ float pk_lo_f(unsigned u) {
    return __builtin_bit_cast(float, u << 16);
}
static __device__ __forceinline__ float pk_hi_f(unsigned u) {
    return __builtin_bit_cast(float, u & 0xffff0000u);
}

// Sum over each 16-lane DPP row via row_shr tree; lane (row*16+15) holds the sum.
static __device__ __forceinline__ float row16_sum(float v) {
    int t;
    t = __builtin_amdgcn_update_dpp(0, __builtin_bit_cast(int, v), 0x111, 0xF, 0xF, true);
    v += __builtin_bit_cast(float, t);
    t = __builtin_amdgcn_update_dpp(0, __builtin_bit_cast(int, v), 0x112, 0xF, 0xF, true);
    v += __builtin_bit_cast(float, t);
    t = __builtin_amdgcn_update_dpp(0, __builtin_bit_cast(int, v), 0x114, 0xF, 0xF, true);
    v += __builtin_bit_cast(float, t);
    t = __builtin_amdgcn_update_dpp(0, __builtin_bit_cast(int, v), 0x118, 0xF, 0xF, true);
    v += __builtin_bit_cast(float, t);
    return v;
}

// R21: LDS gelu-LUT. R20 null (cvt_pk already compiler-handled, guide T12/
// m240). Refined R19-V1 math: 30.2us/rep x 78% VALUBusy / 256 phases-per-
// SIMD = ~110 wave-instrs/phase, VALU-ISSUE-BOUND; Pade gelu (+clamp +2 rcp
// trans per pair) is the dominant block. Fix: 2048-entry bf16 LUT in LDS
// over pre in [-8,8] (step 1/128; max |pre| <= sum of 4 |N(0,0.5)| draws
// ~< 7; gelu saturates beyond +-6 so clamp is exact). Table filled once per
// block with EXACT erf gelu (reference uses approximate=False; the old
// tanh-form Pade carried ~2e-3 approx error -- LUT grid error ~5e-3 w/ b1
// folded into index fma). Per 16 elems: ~56 VALU + 16 ds_read_u16 (LDS pipe
// overlaps VALU) + 8 packs, replacing ~120 VALU + 16 trans. b1 folds into
// the index fma -> layer-1 MFMA C becomes a shared zero quad (kills 16
// v_mov/phase). Everything else frozen from R18/R20: burst gathers +
// sched_barrier, 4 rows/wave, hi/lo k-packed layer-1, re-indexed W2 frag,
// q0-masked y, XCD pin.
__global__ __launch_bounds__(256, 2) void it_kernel(
    const float* __restrict__ y,
    const float* __restrict__ x,
    const float* __restrict__ f_y,
    const float* __restrict__ weights,
    const float* __restrict__ W1,   // [4][64] row-major
    const float* __restrict__ b1,   // [64]
    const float* __restrict__ W2,   // [64][16] row-major
    const float* __restrict__ b2,   // [16]
    const int*   __restrict__ nbr,  // [B][M][K] int32
    float*       __restrict__ out)  // [B][M][16]
{
    __shared__ unsigned short lut[2048];

    const int tid  = threadIdx.x;
    // ---- fill gelu LUT: exact erf-gelu, bf16 values. [-8,8], step 1/128 ----
    #pragma unroll
    for (int i = tid; i < 2048; i += 256) {
        const float xi = (float)(i - 1024) * 0.0078125f;
        const float g  = 0.5f * xi * (1.0f + erff(xi * 0.70710678f));
        lut[i] = (unsigned short)f2bf(g);
    }

    const int lane = tid & 63;
    const int q    = lane >> 4;    // quad 0..3
    const int nlo  = lane & 15;
    const bool q0  = (q == 0);

    const int blk   = blockIdx.x;
    const int batch = blk & 7;          // XCD pin (round-robin heuristic)
    const int pblk  = blk >> 3;         // 0..255 within batch
    const int wid   = tid >> 6;         // wave 0..3
    const int row0  = __builtin_amdgcn_readfirstlane(batch * M_ + pblk * 16 + wid * 4);
    const int bbase = batch * N_;

    // ---- neighbor indices for all 8 phases: issue first ----
    int raw[8];
    #pragma unroll
    for (int ph = 0; ph < 8; ++ph) {
        const int it = ph >> 1, h = ph & 1;
        raw[ph] = nbr[(size_t)(row0 + it) * K_ + h * 16 + nlo];
    }

    // ---- W1^T A-fragments, hi/lo k-packed (R14-validated) ----
    short8 w1h[4];
    #pragma unroll
    for (int t = 0; t < 4; ++t) {
        #pragma unroll
        for (int jj = 0; jj < 4; ++jj) {
            const float wv = W1[jj * HID_ + t * 16 + nlo];
            const short b  = q0 ? f2bf(wv) : (short)0;
            w1h[t][jj]     = b;
            w1h[t][jj + 4] = b;
        }
    }

    // ---- W2 A-fragment with layer-1-layout re-index (R13-validated) ----
    short8 w2f[2];
    #pragma unroll
    for (int ch = 0; ch < 2; ++ch)
        #pragma unroll
        for (int jj = 0; jj < 8; ++jj) {
            const int H = (ch * 2 + (jj >> 2)) * 16 + q * 4 + (jj & 3);
            w2f[ch][jj] = f2bf(W2[H * DOUT_ + nlo]);
        }

    // ---- LUT index bias: 128*b1[hid] + 1024.5 (b1 folded out of MFMA C;
    //      +0.5 gives round-nearest under the truncating cvt) ----
    floatx4 bias4[4];
    #pragma unroll
    for (int t = 0; t < 4; ++t) {
        const floatx4 b1q = *(const floatx4*)(b1 + t * 16 + q * 4);
        bias4[t] = b1q * 128.0f + 1024.5f;
    }
    const floatx4 b2r = *(const floatx4*)(b2 + q * 4);
    const floatx4 zeroq = {0.f, 0.f, 0.f, 0.f};

    // ---- per-row x hi/lo, packed words (4 rows) ----
    unsigned xw_h[4], xw_l[4];
    #pragma unroll
    for (int it = 0; it < 4; ++it) {
        const float2 xv = *(const float2*)(x + (size_t)(row0 + it) * 2);
        const unsigned hw = cvtpk(xv.x, xv.y);
        xw_h[it] = hw;
        xw_l[it] = cvtpk(xv.x - pk_lo_f(hw), xv.y - pk_hi_f(hw));
    }

    // ---- BURST: all 8 phases' gathers issued back-to-back (R18) ----
    float2 yv2[8]; float sw[8]; floatx4 fv[8];
    #pragma unroll
    for (int i = 0; i < 8; ++i) yv2[i] = (float2){0.0f, 0.0f};
    #pragma unroll
    for (int P = 0; P < 8; ++P) {
        const int rv  = raw[P];
        const int vld = rv >= 0;
        const int bn  = bbase + (vld ? rv : 0);
        fv[P] = *(const floatx4*)(f_y + (size_t)bn * 16 + q * 4);
        const float wv_ = weights[bn];
        sw[P] = vld ? wv_ : 0.0f;
        if (q0) yv2[P] = *(const float2*)(y + (size_t)bn * 2);
    }
    __builtin_amdgcn_sched_barrier(0);

    __syncthreads();   // LUT visible (single barrier, setup only)

    float partial[4] = {0.f, 0.f, 0.f, 0.f};
    #pragma unroll
    for (int ph = 0; ph < 8; ++ph) {
        const int it = ph >> 1;

        // ---- input B-fragment via cvt_pk (hi k=0..3, lo k=4..7) ----
        const float y0 = yv2[ph].x, y1 = yv2[ph].y;
        const unsigned yw_h = cvtpk(y0, y1);
        const unsigned yw_l = cvtpk(y0 - pk_lo_f(yw_h), y1 - pk_hi_f(yw_h));
        const uint4v bw = { yw_h, xw_h[it], yw_l, xw_l[it] };
        const short8 bfull = __builtin_bit_cast(short8, bw);

        // ---- layer 1: one MFMA per 16-hid tile, C = shared zero quad ----
        floatx4 a1[4];
        #pragma unroll
        for (int t = 0; t < 4; ++t)
            a1[t] = __builtin_amdgcn_mfma_f32_16x16x32_bf16(w1h[t], bfull, zeroq, 0, 0, 0);

        // ---- gelu via LDS LUT: idx = clamp(fma(pre,128,bias),0,2047);
        //      packed index math, ds_read_u16, pack pairs into B-frag words ----
        unsigned hw[8];
        #pragma unroll
        for (int t = 0; t < 4; ++t) {
            f32x2 i01 = __builtin_elementwise_fma(
                (f32x2){a1[t][0], a1[t][1]}, splat2(128.0f),
                (f32x2){bias4[t][0], bias4[t][1]});
            f32x2 i23 = __builtin_elementwise_fma(
                (f32x2){a1[t][2], a1[t][3]}, splat2(128.0f),
                (f32x2){bias4[t][2], bias4[t][3]});
            i01 = __builtin_elementwise_min(
                      __builtin_elementwise_max(i01, splat2(0.0f)), splat2(2047.0f));
            i23 = __builtin_elementwise_min(
                      __builtin_elementwise_max(i23, splat2(0.0f)), splat2(2047.0f));
            const unsigned short l0 = lut[(unsigned)i01[0]];
            const unsigned short l1 = lut[(unsigned)i01[1]];
            const unsigned short l2 = lut[(unsigned)i23[0]];
            const unsigned short l3 = lut[(unsigned)i23[1]];
            hw[t * 2 + 0] = (unsigned)l0 | ((unsigned)l1 << 16);
            hw[t * 2 + 1] = (unsigned)l2 | ((unsigned)l3 << 16);
        }
        const uint4v h0w = { hw[0], hw[1], hw[2], hw[3] };
        const uint4v h1w = { hw[4], hw[5], hw[6], hw[7] };
        const short8 hf0 = __builtin_bit_cast(short8, h0w);
        const short8 hf1 = __builtin_bit_cast(short8, h1w);

        // ---- layer 2: kval[c][elem] = W2^T . h + b2 ----
        floatx4 acc = b2r;
        acc = __builtin_amdgcn_mfma_f32_16x16x32_bf16(w2f[0], hf0, acc, 0, 0, 0);
        acc = __builtin_amdgcn_mfma_f32_16x16x32_bf16(w2f[1], hf1, acc, 0, 0, 0);

        const floatx4 fvp = fv[ph];
        const float   s   = sw[ph];          // 0 for invalid neighbors
        #pragma unroll
        for (int r = 0; r < 4; ++r)
            partial[r] = fmaf(acc[r], fvp[r] * s, partial[r]);

        if (ph & 1) {   // finished a row: reduce over 16 elem-lanes, store
            #pragma unroll
            for (int r = 0; r < 4; ++r) partial[r] = row16_sum(partial[r]);
            if (nlo == 15) {
                floatx4 o = {partial[0], partial[1], partial[2], partial[3]};
                *(floatx4*)(out + (size_t)(row0 + it) * DOUT_ + q * 4) = o;
            }
            #pragma unroll
            for (int r = 0; r < 4; ++r) partial[r] = 0.f;
        }
    }
}

extern "C" void kernel_launch(void* const* d_in, const int* in_sizes, int n_in,
                              void* d_out, int out_size, void* d_ws, size_t ws_size,
                              hipStream_t stream) {
    const float* y   = (const float*)d_in[0];
    const float* x   = (const float*)d_in[1];
    const float* f_y = (const float*)d_in[2];
    const float* w   = (const float*)d_in[3];
    const float* W1  = (const float*)d_in[4];
    const float* b1  = (const float*)d_in[5];
    const float* W2  = (const float*)d_in[6];
    const float* b2  = (const float*)d_in[7];
    const int*   nbr = (const int*)d_in[8];
    float* out = (float*)d_out;

    // Single dispatch. 2048 blocks: 256 per batch (16 rows/block),
    // batch = blk & 7 -> XCD pin.
    dim3 grid(B_ * M_ / 16), block(256);
    hipLaunchKernelGGL(it_kernel, grid, block, 0, stream,
                       y, x, f_y, w, W1, b1, W2, b2, nbr, out);
}

// Round 11
// 102.867 us; speedup vs baseline: 2.2528x; 1.0109x over previous
//
#include <hip/hip_runtime.h>
#include <hip/hip_bf16.h>
#include <math.h>

#define B_    8
#define N_    9225
#define M_    4096
#define K_    32
#define HID_  64
#define DOUT_ 16

typedef __attribute__((ext_vector_type(8))) short short8;
typedef __attribute__((ext_vector_type(4))) float floatx4;
typedef __attribute__((ext_vector_type(2))) float f32x2;
typedef __attribute__((ext_vector_type(4))) unsigned uint4v;

static __device__ __forceinline__ short f2bf(float f) {
    __hip_bfloat16 h = __float2bfloat16(f);
    return __builtin_bit_cast(short, h);
}
static __device__ __forceinline__ f32x2 splat2(float v) { return (f32x2){v, v}; }

static __device__ __forceinline__ unsigned cvtpk(float a, float b) {
    unsigned r;
    asm("v_cvt_pk_bf16_f32 %0, %1, %2" : "=v"(r) : "v"(a), "v"(b));
    return r;
}
static __device__ __forceinline__ float pk_lo_f(unsigned u) {
    return __builtin_bit_cast(float, u << 16);
}
static __device__ __forceinline__ float pk_hi_f(unsigned u) {
    return __builtin_bit_cast(float, u & 0xffff0000u);
}

// Scattered gather DIRECT to LDS: global source address is per-lane; LDS
// dest must be the wave-uniform slab base -- HW writes base + lane*16.
static __device__ __forceinline__ void gload_lds16(const float* g, float* lds_base) {
    __builtin_amdgcn_global_load_lds(
        (const __attribute__((address_space(1))) void*)g,
        (__attribute__((address_space(3))) void*)lds_base, 16, 0, 0);
}

// Sum over each 16-lane DPP row via row_shr tree; lane (row*16+15) holds the sum.
static __device__ __forceinline__ float row16_sum(float v) {
    int t;
    t = __builtin_amdgcn_update_dpp(0, __builtin_bit_cast(int, v), 0x111, 0xF, 0xF, true);
    v += __builtin_bit_cast(float, t);
    t = __builtin_amdgcn_update_dpp(0, __builtin_bit_cast(int, v), 0x112, 0xF, 0xF, true);
    v += __builtin_bit_cast(float, t);
    t = __builtin_amdgcn_update_dpp(0, __builtin_bit_cast(int, v), 0x114, 0xF, 0xF, true);
    v += __builtin_bit_cast(float, t);
    t = __builtin_amdgcn_update_dpp(0, __builtin_bit_cast(int, v), 0x118, 0xF, 0xF, true);
    v += __builtin_bit_cast(float, t);
    return v;
}

// R22: register-file attack. Session ledger resolved: VALUBusy is CU-level
// (real per-SIMD issue ~25%); OccupancyPercent 30-36% every round matches
// live state ~170 regs (incl MFMA accs in the unified VGPR/AGPR file that
// the CSV's VGPR_Count under-reports) -> 3 waves/SIMD on a 512-reg pool.
// Binder = dependency latency x 3-wave residency; VALU cuts were never it;
// R14's "50% occ, same time" = freed regs by sinking the pipeline (deeper
// stalls offset). Fix: take the 8-phase fv burst OUT of the register file --
// global_load_lds scatters f_y rows directly into a wave-private 8KB LDS
// slab (-32 VGPR, pipeline depth kept); y/w stay in regs; single drain at
// the existing __syncthreads (also publishes LUT). Plus: W1 pre-scaled by
// 128 (exact pow2) + MFMA C = 128*b1+1024.5 -> a1 IS the LUT index (-4
// pk_fma/phase, -4 zero regs). launch_bounds(256,4) pins alloc <=128 ->
// 4 waves/SIMD. Everything else frozen from R21.
__global__ __launch_bounds__(256, 4) void it_kernel(
    const float* __restrict__ y,
    const float* __restrict__ x,
    const float* __restrict__ f_y,
    const float* __restrict__ weights,
    const float* __restrict__ W1,   // [4][64] row-major
    const float* __restrict__ b1,   // [64]
    const float* __restrict__ W2,   // [64][16] row-major
    const float* __restrict__ b2,   // [16]
    const int*   __restrict__ nbr,  // [B][M][K] int32
    float*       __restrict__ out)  // [B][M][16]
{
    __shared__ unsigned short lut[2048];        // 4KB gelu table
    __shared__ float stg[4][8][256];            // 32KB: wave x phase x lane*4

    const int tid  = threadIdx.x;
    // ---- fill gelu LUT: exact erf-gelu, bf16 values. [-8,8], step 1/128 ----
    #pragma unroll
    for (int i = tid; i < 2048; i += 256) {
        const float xi = (float)(i - 1024) * 0.0078125f;
        const float g  = 0.5f * xi * (1.0f + erff(xi * 0.70710678f));
        lut[i] = (unsigned short)f2bf(g);
    }

    const int lane = tid & 63;
    const int q    = lane >> 4;    // quad 0..3
    const int nlo  = lane & 15;
    const bool q0  = (q == 0);

    const int blk   = blockIdx.x;
    const int batch = blk & 7;          // XCD pin (round-robin heuristic)
    const int pblk  = blk >> 3;         // 0..255 within batch
    const int wid   = tid >> 6;         // wave 0..3
    const int row0  = __builtin_amdgcn_readfirstlane(batch * M_ + pblk * 16 + wid * 4);
    const int bbase = batch * N_;

    // ---- neighbor indices for all 8 phases: issue first ----
    int raw[8];
    #pragma unroll
    for (int ph = 0; ph < 8; ++ph) {
        const int it = ph >> 1, h = ph & 1;
        raw[ph] = nbr[(size_t)(row0 + it) * K_ + h * 16 + nlo];
    }

    // ---- W1^T A-fragments, hi/lo k-packed, PRE-SCALED by 128 (exact pow2:
    //      bf16(128*w) == 128*bf16(w)) so layer-1 MFMA output is the LUT
    //      index directly (with C = 128*b1 + 1024.5) ----
    short8 w1h[4];
    #pragma unroll
    for (int t = 0; t < 4; ++t) {
        #pragma unroll
        for (int jj = 0; jj < 4; ++jj) {
            const float wv = W1[jj * HID_ + t * 16 + nlo] * 128.0f;
            const short b  = q0 ? f2bf(wv) : (short)0;
            w1h[t][jj]     = b;
            w1h[t][jj + 4] = b;
        }
    }

    // ---- W2 A-fragment with layer-1-layout re-index (R13-validated) ----
    short8 w2f[2];
    #pragma unroll
    for (int ch = 0; ch < 2; ++ch)
        #pragma unroll
        for (int jj = 0; jj < 8; ++jj) {
            const int H = (ch * 2 + (jj >> 2)) * 16 + q * 4 + (jj & 3);
            w2f[ch][jj] = f2bf(W2[H * DOUT_ + nlo]);
        }

    // ---- LUT-index bias as layer-1 MFMA C operand: 128*b1 + 1024.5 ----
    floatx4 biasC[4];
    #pragma unroll
    for (int t = 0; t < 4; ++t) {
        const floatx4 b1q = *(const floatx4*)(b1 + t * 16 + q * 4);
        biasC[t] = b1q * 128.0f + 1024.5f;
    }
    const floatx4 b2r = *(const floatx4*)(b2 + q * 4);

    // ---- per-row x hi/lo, packed words (4 rows) ----
    unsigned xw_h[4], xw_l[4];
    #pragma unroll
    for (int it = 0; it < 4; ++it) {
        const float2 xv = *(const float2*)(x + (size_t)(row0 + it) * 2);
        const unsigned hw = cvtpk(xv.x, xv.y);
        xw_h[it] = hw;
        xw_l[it] = cvtpk(xv.x - pk_lo_f(hw), xv.y - pk_hi_f(hw));
    }

    // ---- BURST: fv -> LDS slab (no VGPR cost), y/w -> regs ----
    float2 yv2[8]; float sw[8];
    #pragma unroll
    for (int i = 0; i < 8; ++i) yv2[i] = (float2){0.0f, 0.0f};
    #pragma unroll
    for (int P = 0; P < 8; ++P) {
        const int rv  = raw[P];
        const int vld = rv >= 0;
        const int bn  = bbase + (vld ? rv : 0);
        gload_lds16(f_y + (size_t)bn * 16 + q * 4, &stg[wid][P][0]);
        const float wv_ = weights[bn];
        sw[P] = vld ? wv_ : 0.0f;
        if (q0) yv2[P] = *(const float2*)(y + (size_t)bn * 2);
    }

    // Single drain: __syncthreads waits vmcnt(0)+lgkmcnt(0) (burst + y/w
    // complete, LUT visible). sched_barrier keeps compute below it.
    __syncthreads();
    __builtin_amdgcn_sched_barrier(0);

    float partial[4] = {0.f, 0.f, 0.f, 0.f};
    #pragma unroll
    for (int ph = 0; ph < 8; ++ph) {
        const int it = ph >> 1;

        // fv slice from the LDS slab (ds_read_b128, issued early in phase)
        const floatx4 fvp = *(const floatx4*)&stg[wid][ph][lane * 4];

        // ---- input B-fragment via cvt_pk (hi k=0..3, lo k=4..7) ----
        const float y0 = yv2[ph].x, y1 = yv2[ph].y;
        const unsigned yw_h = cvtpk(y0, y1);
        const unsigned yw_l = cvtpk(y0 - pk_lo_f(yw_h), y1 - pk_hi_f(yw_h));
        const uint4v bw = { yw_h, xw_h[it], yw_l, xw_l[it] };
        const short8 bfull = __builtin_bit_cast(short8, bw);

        // ---- layer 1: a1[t] = 128*(W1^T.in + b1) + 1024.5 == LUT index ----
        floatx4 a1[4];
        #pragma unroll
        for (int t = 0; t < 4; ++t)
            a1[t] = __builtin_amdgcn_mfma_f32_16x16x32_bf16(w1h[t], bfull, biasC[t], 0, 0, 0);

        // ---- gelu via LDS LUT: clamp packed, cvt, ds_read_u16, pack ----
        unsigned hw[8];
        #pragma unroll
        for (int t = 0; t < 4; ++t) {
            f32x2 i01 = {a1[t][0], a1[t][1]};
            f32x2 i23 = {a1[t][2], a1[t][3]};
            i01 = __builtin_elementwise_min(
                      __builtin_elementwise_max(i01, splat2(0.0f)), splat2(2047.0f));
            i23 = __builtin_elementwise_min(
                      __builtin_elementwise_max(i23, splat2(0.0f)), splat2(2047.0f));
            const unsigned short l0 = lut[(unsigned)i01[0]];
            const unsigned short l1 = lut[(unsigned)i01[1]];
            const unsigned short l2 = lut[(unsigned)i23[0]];
            const unsigned short l3 = lut[(unsigned)i23[1]];
            hw[t * 2 + 0] = (unsigned)l0 | ((unsigned)l1 << 16);
            hw[t * 2 + 1] = (unsigned)l2 | ((unsigned)l3 << 16);
        }
        const uint4v h0w = { hw[0], hw[1], hw[2], hw[3] };
        const uint4v h1w = { hw[4], hw[5], hw[6], hw[7] };
        const short8 hf0 = __builtin_bit_cast(short8, h0w);
        const short8 hf1 = __builtin_bit_cast(short8, h1w);

        // ---- layer 2: kval[c][elem] = W2^T . h + b2 ----
        floatx4 acc = b2r;
        acc = __builtin_amdgcn_mfma_f32_16x16x32_bf16(w2f[0], hf0, acc, 0, 0, 0);
        acc = __builtin_amdgcn_mfma_f32_16x16x32_bf16(w2f[1], hf1, acc, 0, 0, 0);

        const float s = sw[ph];          // 0 for invalid neighbors
        #pragma unroll
        for (int r = 0; r < 4; ++r)
            partial[r] = fmaf(acc[r], fvp[r] * s, partial[r]);

        if (ph & 1) {   // finished a row: reduce over 16 elem-lanes, store
            #pragma unroll
            for (int r = 0; r < 4; ++r) partial[r] = row16_sum(partial[r]);
            if (nlo == 15) {
                floatx4 o = {partial[0], partial[1], partial[2], partial[3]};
                *(floatx4*)(out + (size_t)(row0 + it) * DOUT_ + q * 4) = o;
            }
            #pragma unroll
            for (int r = 0; r < 4; ++r) partial[r] = 0.f;
        }
    }
}

extern "C" void kernel_launch(void* const* d_in, const int* in_sizes, int n_in,
                              void* d_out, int out_size, void* d_ws, size_t ws_size,
                              hipStream_t stream) {
    const float* y   = (const float*)d_in[0];
    const float* x   = (const float*)d_in[1];
    const float* f_y = (const float*)d_in[2];
    const float* w   = (const float*)d_in[3];
    const float* W1  = (const float*)d_in[4];
    const float* b1  = (const float*)d_in[5];
    const float* W2  = (const float*)d_in[6];
    const float* b2  = (const float*)d_in[7];
    const int*   nbr = (const int*)d_in[8];
    float* out = (float*)d_out;

    // Single dispatch. 2048 blocks: 256 per batch (16 rows/block),
    // batch = blk & 7 -> XCD pin.
    dim3 grid(B_ * M_ / 16), block(256);
    hipLaunchKernelGGL(it_kernel, grid, block, 0, stream,
                       y, x, f_y, w, W1, b1, W2, b2, nbr, out);
}

// Round 12
// 102.390 us; speedup vs baseline: 2.2633x; 1.0047x over previous
//
#include <hip/hip_runtime.h>
#include <hip/hip_bf16.h>
#include <math.h>

#define B_    8
#define N_    9225
#define M_    4096
#define K_    32
#define HID_  64
#define DOUT_ 16

typedef __attribute__((ext_vector_type(8))) short short8;
typedef __attribute__((ext_vector_type(4))) float floatx4;
typedef __attribute__((ext_vector_type(2))) float f32x2;
typedef __attribute__((ext_vector_type(4))) unsigned uint4v;

static __device__ __forceinline__ short f2bf(float f) {
    __hip_bfloat16 h = __float2bfloat16(f);
    return __builtin_bit_cast(short, h);
}
static __device__ __forceinline__ f32x2 splat2(float v) { return (f32x2){v, v}; }

static __device__ __forceinline__ unsigned cvtpk(float a, float b) {
    unsigned r;
    asm("v_cvt_pk_bf16_f32 %0, %1, %2" : "=v"(r) : "v"(a), "v"(b));
    return r;
}
static __device__ __forceinline__ float pk_lo_f(unsigned u) {
    return __builtin_bit_cast(float, u << 16);
}
static __device__ __forceinline__ float pk_hi_f(unsigned u) {
    return __builtin_bit_cast(float, u & 0xffff0000u);
}

// Scattered gather DIRECT to LDS: global source address is per-lane; LDS
// dest is the wave-uniform slab base -- HW writes base + lane*16.
static __device__ __forceinline__ void gload_lds16(const float* g, float* lds_base) {
    __builtin_amdgcn_global_load_lds(
        (const __attribute__((address_space(1))) void*)g,
        (__attribute__((address_space(3))) void*)lds_base, 16, 0, 0);
}

// Sum over each 16-lane DPP row via row_shr tree; lane (row*16+15) holds the sum.
static __device__ __forceinline__ float row16_sum(float v) {
    int t;
    t = __builtin_amdgcn_update_dpp(0, __builtin_bit_cast(int, v), 0x111, 0xF, 0xF, true);
    v += __builtin_bit_cast(float, t);
    t = __builtin_amdgcn_update_dpp(0, __builtin_bit_cast(int, v), 0x112, 0xF, 0xF, true);
    v += __builtin_bit_cast(float, t);
    t = __builtin_amdgcn_update_dpp(0, __builtin_bit_cast(int, v), 0x114, 0xF, 0xF, true);
    v += __builtin_bit_cast(float, t);
    t = __builtin_amdgcn_update_dpp(0, __builtin_bit_cast(int, v), 0x118, 0xF, 0xF, true);
    v += __builtin_bit_cast(float, t);
    return v;
}

// R23: chain-latency attack. Cycle model finally closes (R19-V1: 283 cyc/CU/
// phase = 220 VALU-issue + 30 MFMA + 33 misc; VALUBusy is CU-level OR-
// semantics -> ~19% per-SIMD issue; R13/R14's VALU-30%-null refutes issue-
// saturation) -> compute is DEPENDENCY-LATENCY-bound: each phase is one
// serial chain (ycvt -> L1 MFMA -> clamp/cvt -> LUT ds_read -> pack -> L2
// MFMA x2 -> fmaf) and launch_bounds(256,4) left no registers to keep two
// phases' intermediates live, so the unrolled phases serialized. Fix:
// (1) manual 2-phase interleave -- each row's two half-phases (independent
// until the partial accumulate) computed side by side: 2 chains/wave;
// (2) all 8 phases' y hi/lo words pre-converted once after the drain
// (removes per-phase chain head; frees yv2, net 0 regs);
// (3) launch_bounds(256,3): dual-phase live state ~170 regs fits 3 waves/
// SIMD x 170 <= 512 without spill (LDS caps blocks at 4/CU anyway).
// Everything else frozen from R22: fv via global_load_lds slab, erf-gelu
// LDS LUT, W1 pre-scaled 128 + bias-as-C (a1 IS the LUT index), hi/lo
// k-packed layer-1, re-indexed W2 frag, q0-masked y, burst+sched_barrier,
// XCD pin.
__global__ __launch_bounds__(256, 3) void it_kernel(
    const float* __restrict__ y,
    const float* __restrict__ x,
    const float* __restrict__ f_y,
    const float* __restrict__ weights,
    const float* __restrict__ W1,   // [4][64] row-major
    const float* __restrict__ b1,   // [64]
    const float* __restrict__ W2,   // [64][16] row-major
    const float* __restrict__ b2,   // [16]
    const int*   __restrict__ nbr,  // [B][M][K] int32
    float*       __restrict__ out)  // [B][M][16]
{
    __shared__ unsigned short lut[2048];        // 4KB gelu table
    __shared__ float stg[4][8][256];            // 32KB: wave x phase x lane*4

    const int tid  = threadIdx.x;
    // ---- fill gelu LUT: exact erf-gelu, bf16 values. [-8,8], step 1/128 ----
    #pragma unroll
    for (int i = tid; i < 2048; i += 256) {
        const float xi = (float)(i - 1024) * 0.0078125f;
        const float g  = 0.5f * xi * (1.0f + erff(xi * 0.70710678f));
        lut[i] = (unsigned short)f2bf(g);
    }

    const int lane = tid & 63;
    const int q    = lane >> 4;    // quad 0..3
    const int nlo  = lane & 15;
    const bool q0  = (q == 0);

    const int blk   = blockIdx.x;
    const int batch = blk & 7;          // XCD pin (round-robin heuristic)
    const int pblk  = blk >> 3;         // 0..255 within batch
    const int wid   = tid >> 6;         // wave 0..3
    const int row0  = __builtin_amdgcn_readfirstlane(batch * M_ + pblk * 16 + wid * 4);
    const int bbase = batch * N_;

    // ---- neighbor indices for all 8 phases: issue first ----
    int raw[8];
    #pragma unroll
    for (int ph = 0; ph < 8; ++ph) {
        const int it = ph >> 1, h = ph & 1;
        raw[ph] = nbr[(size_t)(row0 + it) * K_ + h * 16 + nlo];
    }

    // ---- W1^T A-fragments, hi/lo k-packed, pre-scaled by 128 (exact pow2) ----
    short8 w1h[4];
    #pragma unroll
    for (int t = 0; t < 4; ++t) {
        #pragma unroll
        for (int jj = 0; jj < 4; ++jj) {
            const float wv = W1[jj * HID_ + t * 16 + nlo] * 128.0f;
            const short b  = q0 ? f2bf(wv) : (short)0;
            w1h[t][jj]     = b;
            w1h[t][jj + 4] = b;
        }
    }

    // ---- W2 A-fragment with layer-1-layout re-index (R13-validated) ----
    short8 w2f[2];
    #pragma unroll
    for (int ch = 0; ch < 2; ++ch)
        #pragma unroll
        for (int jj = 0; jj < 8; ++jj) {
            const int H = (ch * 2 + (jj >> 2)) * 16 + q * 4 + (jj & 3);
            w2f[ch][jj] = f2bf(W2[H * DOUT_ + nlo]);
        }

    // ---- LUT-index bias as layer-1 MFMA C operand: 128*b1 + 1024.5 ----
    floatx4 biasC[4];
    #pragma unroll
    for (int t = 0; t < 4; ++t) {
        const floatx4 b1q = *(const floatx4*)(b1 + t * 16 + q * 4);
        biasC[t] = b1q * 128.0f + 1024.5f;
    }
    const floatx4 b2r = *(const floatx4*)(b2 + q * 4);

    // ---- per-row x hi/lo, packed words (4 rows) ----
    unsigned xw_h[4], xw_l[4];
    #pragma unroll
    for (int it = 0; it < 4; ++it) {
        const float2 xv = *(const float2*)(x + (size_t)(row0 + it) * 2);
        const unsigned hw = cvtpk(xv.x, xv.y);
        xw_h[it] = hw;
        xw_l[it] = cvtpk(xv.x - pk_lo_f(hw), xv.y - pk_hi_f(hw));
    }

    // ---- BURST: fv -> LDS slab (no VGPR cost), y/w -> regs ----
    float2 yv2[8]; float sw[8];
    #pragma unroll
    for (int i = 0; i < 8; ++i) yv2[i] = (float2){0.0f, 0.0f};
    #pragma unroll
    for (int P = 0; P < 8; ++P) {
        const int rv  = raw[P];
        const int vld = rv >= 0;
        const int bn  = bbase + (vld ? rv : 0);
        gload_lds16(f_y + (size_t)bn * 16 + q * 4, &stg[wid][P][0]);
        const float wv_ = weights[bn];
        sw[P] = vld ? wv_ : 0.0f;
        if (q0) yv2[P] = *(const float2*)(y + (size_t)bn * 2);
    }

    // Single drain: __syncthreads waits vmcnt(0)+lgkmcnt(0) (burst + y/w
    // complete, LUT visible). sched_barrier keeps compute below it.
    __syncthreads();
    __builtin_amdgcn_sched_barrier(0);

    // ---- pre-convert ALL phases' y hi/lo words (hoisted off the chains) ----
    unsigned yw_h8[8], yw_l8[8];
    #pragma unroll
    for (int P = 0; P < 8; ++P) {
        const float y0 = yv2[P].x, y1 = yv2[P].y;
        const unsigned hw_ = cvtpk(y0, y1);
        yw_h8[P] = hw_;
        yw_l8[P] = cvtpk(y0 - pk_lo_f(hw_), y1 - pk_hi_f(hw_));
    }

    float partial[4] = {0.f, 0.f, 0.f, 0.f};
    #pragma unroll
    for (int it = 0; it < 4; ++it) {
        const int pa = 2 * it, pb = 2 * it + 1;

        // fv slices for both half-phases (ds_read_b128, issued up front)
        const floatx4 fva = *(const floatx4*)&stg[wid][pa][lane * 4];
        const floatx4 fvb = *(const floatx4*)&stg[wid][pb][lane * 4];

        // ---- both B-fragments (pure bit assembly from precomputed words) ----
        const uint4v bwa = { yw_h8[pa], xw_h[it], yw_l8[pa], xw_l[it] };
        const uint4v bwb = { yw_h8[pb], xw_h[it], yw_l8[pb], xw_l[it] };
        const short8 bfa = __builtin_bit_cast(short8, bwa);
        const short8 bfb = __builtin_bit_cast(short8, bwb);

        // ---- layer 1, two independent chains interleaved ----
        floatx4 a1a[4], a1b[4];
        #pragma unroll
        for (int t = 0; t < 4; ++t) {
            a1a[t] = __builtin_amdgcn_mfma_f32_16x16x32_bf16(w1h[t], bfa, biasC[t], 0, 0, 0);
            a1b[t] = __builtin_amdgcn_mfma_f32_16x16x32_bf16(w1h[t], bfb, biasC[t], 0, 0, 0);
        }

        // ---- gelu LUT for both chains, interleaved ----
        unsigned hwa[8], hwb[8];
        #pragma unroll
        for (int t = 0; t < 4; ++t) {
            f32x2 ia01 = {a1a[t][0], a1a[t][1]}, ia23 = {a1a[t][2], a1a[t][3]};
            f32x2 ib01 = {a1b[t][0], a1b[t][1]}, ib23 = {a1b[t][2], a1b[t][3]};
            ia01 = __builtin_elementwise_min(
                       __builtin_elementwise_max(ia01, splat2(0.0f)), splat2(2047.0f));
            ia23 = __builtin_elementwise_min(
                       __builtin_elementwise_max(ia23, splat2(0.0f)), splat2(2047.0f));
            ib01 = __builtin_elementwise_min(
                       __builtin_elementwise_max(ib01, splat2(0.0f)), splat2(2047.0f));
            ib23 = __builtin_elementwise_min(
                       __builtin_elementwise_max(ib23, splat2(0.0f)), splat2(2047.0f));
            const unsigned short a0 = lut[(unsigned)ia01[0]];
            const unsigned short a1v = lut[(unsigned)ia01[1]];
            const unsigned short a2 = lut[(unsigned)ia23[0]];
            const unsigned short a3 = lut[(unsigned)ia23[1]];
            const unsigned short c0 = lut[(unsigned)ib01[0]];
            const unsigned short c1 = lut[(unsigned)ib01[1]];
            const unsigned short c2 = lut[(unsigned)ib23[0]];
            const unsigned short c3 = lut[(unsigned)ib23[1]];
            hwa[t * 2 + 0] = (unsigned)a0 | ((unsigned)a1v << 16);
            hwa[t * 2 + 1] = (unsigned)a2 | ((unsigned)a3 << 16);
            hwb[t * 2 + 0] = (unsigned)c0 | ((unsigned)c1 << 16);
            hwb[t * 2 + 1] = (unsigned)c2 | ((unsigned)c3 << 16);
        }
        const short8 hf0a = __builtin_bit_cast(short8, (uint4v){hwa[0], hwa[1], hwa[2], hwa[3]});
        const short8 hf1a = __builtin_bit_cast(short8, (uint4v){hwa[4], hwa[5], hwa[6], hwa[7]});
        const short8 hf0b = __builtin_bit_cast(short8, (uint4v){hwb[0], hwb[1], hwb[2], hwb[3]});
        const short8 hf1b = __builtin_bit_cast(short8, (uint4v){hwb[4], hwb[5], hwb[6], hwb[7]});

        // ---- layer 2, both chains interleaved ----
        floatx4 acca = b2r, accb = b2r;
        acca = __builtin_amdgcn_mfma_f32_16x16x32_bf16(w2f[0], hf0a, acca, 0, 0, 0);
        accb = __builtin_amdgcn_mfma_f32_16x16x32_bf16(w2f[0], hf0b, accb, 0, 0, 0);
        acca = __builtin_amdgcn_mfma_f32_16x16x32_bf16(w2f[1], hf1a, acca, 0, 0, 0);
        accb = __builtin_amdgcn_mfma_f32_16x16x32_bf16(w2f[1], hf1b, accb, 0, 0, 0);

        // ---- accumulate both half-phases, reduce over 16 lanes, store row ----
        const float sa = sw[pa], sb = sw[pb];
        #pragma unroll
        for (int r = 0; r < 4; ++r) {
            partial[r] = fmaf(acca[r], fva[r] * sa, partial[r]);
            partial[r] = fmaf(accb[r], fvb[r] * sb, partial[r]);
        }
        #pragma unroll
        for (int r = 0; r < 4; ++r) partial[r] = row16_sum(partial[r]);
        if (nlo == 15) {
            floatx4 o = {partial[0], partial[1], partial[2], partial[3]};
            *(floatx4*)(out + (size_t)(row0 + it) * DOUT_ + q * 4) = o;
        }
        #pragma unroll
        for (int r = 0; r < 4; ++r) partial[r] = 0.f;
    }
}

extern "C" void kernel_launch(void* const* d_in, const int* in_sizes, int n_in,
                              void* d_out, int out_size, void* d_ws, size_t ws_size,
                              hipStream_t stream) {
    const float* y   = (const float*)d_in[0];
    const float* x   = (const float*)d_in[1];
    const float* f_y = (const float*)d_in[2];
    const float* w   = (const float*)d_in[3];
    const float* W1  = (const float*)d_in[4];
    const float* b1  = (const float*)d_in[5];
    const float* W2  = (const float*)d_in[6];
    const float* b2  = (const float*)d_in[7];
    const int*   nbr = (const int*)d_in[8];
    float* out = (float*)d_out;

    // Single dispatch. 2048 blocks: 256 per batch (16 rows/block),
    // batch = blk & 7 -> XCD pin.
    dim3 grid(B_ * M_ / 16), block(256);
    hipLaunchKernelGGL(it_kernel, grid, block, 0, stream,
                       y, x, f_y, w, W1, b1, W2, b2, nbr, out);
}